// Round 13
// baseline (698.567 us; speedup 1.0000x reference)
//
// R23: gru occupancy 2->3 blocks/CU. R22 counters: gru #1 at 199us, Occ 20%,
// MfmaUtil 7%, VALU 20% -- latency-bound at the VGPR cap (116 arch + 64 AGPR
// acc[16] ~ 180 > 170). Fix: stage-2 gates in 4 passes of N=128 (acc[8], 32
// AGPR), carries r/z/gi as packed bf16 (v_cvt_pk, 48 regs); B_lds 16->8KB ->
// LDS 41984 -> 3 blocks/CU with __launch_bounds__(256,3). Same MFMA count,
// same staged bytes. Revert trigger: gru WRITE_SIZE >> 50MB (spill).
#include <hip/hip_runtime.h>

#define G_KP 20
#define G_LN_EPS 1e-5f

typedef float v4f __attribute__((ext_vector_type(4)));
typedef short v8s __attribute__((ext_vector_type(8)));
typedef short v4s __attribute__((ext_vector_type(4)));

__device__ __forceinline__ unsigned short f2b(float x) {
  union { float f; unsigned int i; } c;
  c.f = x;
  return (unsigned short)((c.i + 0x7FFFu + ((c.i >> 16) & 1u)) >> 16);
}
__device__ __forceinline__ float b2f(unsigned short u) {
  union { unsigned int i; float f; } c;
  c.i = ((unsigned int)u) << 16;
  return c.f;
}
__device__ __forceinline__ float bits2f(unsigned int i) {
  union { unsigned int i; float f; } c;
  c.i = i;
  return c.f;
}
// 2x f32 -> packed bf16 (RNE): lo -> low16, hi -> high16
__device__ __forceinline__ unsigned int cvtpk(float lo, float hi) {
  unsigned int r;
  asm("v_cvt_pk_bf16_f32 %0, %1, %2" : "=v"(r) : "v"(lo), "v"(hi));
  return r;
}
__device__ __forceinline__ float unpk(unsigned int pk, int odd) {
  return odd ? bits2f(pk & 0xFFFF0000u) : bits2f(pk << 16);
}
__device__ __forceinline__ float sigm(float x) {
  return 1.0f / (1.0f + __expf(-fmaxf(fminf(x, 30.0f), -30.0f)));
}

// Shared-B MFMA stage: stages NTS tiles/kt cooperatively; each wave MFMAs
// NTU tiles starting at B-tile offset b_off (v8s units).
template<int NKT, int NTS, int NTU>
__device__ __forceinline__ void stage_mfma2(
    const v8s* __restrict__ Bsrc, int kt_tiles, v8s* B_lds,
    const unsigned short* Arow, int a_kt, int a_off, int b_off,
    int t, int l, v4f* acc) {
  constexpr int NPR = NTS / 4;
  v8s pr[NPR];
  #pragma unroll
  for (int i = 0; i < NPR; ++i) pr[i] = Bsrc[t + i * 256];
  #pragma unroll
  for (int kt = 0; kt < NKT; ++kt) {
    __syncthreads();
    #pragma unroll
    for (int i = 0; i < NPR; ++i) B_lds[t + i * 256] = pr[i];
    if (kt + 1 < NKT) {
      #pragma unroll
      for (int i = 0; i < NPR; ++i)
        pr[i] = Bsrc[(kt + 1) * kt_tiles * 64 + t + i * 256];
    }
    __syncthreads();
    v8s a = *(const v8s*)&Arow[kt * a_kt + a_off];
    #pragma unroll
    for (int n0 = 0; n0 < NTU; ++n0)
      acc[n0] = __builtin_amdgcn_mfma_f32_16x16x32_bf16(a, B_lds[b_off + n0 * 64 + l], acc[n0], 0, 0, 0);
  }
}

// original stub symbol (kept; harmless)
__global__ void GNNLayerKAFP_76871324663923_kernel() {}

__global__ void k_fill(float* out, int n, float v) {
  int i = blockIdx.x * 256 + threadIdx.x;
  if (i < n) out[i] = v;
}

__global__ void k_zero(float* p, int n) {
  int i = blockIdx.x * 256 + threadIdx.x;
  if (i < n) p[i] = 0.0f;
}

// ---- B-fragment packers (unchanged) ----
__global__ void k_prep_wk2b(const float* Wk2, unsigned short* Wk2b) {
  int id = blockIdx.x * 256 + threadIdx.x;
  if (id >= 13 * 8 * 64 * 8) return;
  int j = id & 7, l = (id >> 3) & 63, n0 = (id >> 9) & 7, kt = id >> 12;
  int k = kt * 32 + (l >> 4) * 8 + j;
  int n = n0 * 16 + (l & 15);
  Wk2b[id] = f2b((k < 400) ? Wk2[k * 128 + n] : 0.0f);
}

__global__ void k_prep_wpnb(const float* Wpn, unsigned short* WpnB) {
  int id = blockIdx.x * 256 + threadIdx.x;
  if (id >= 4 * 8 * 64 * 8) return;
  int j = id & 7, l = (id >> 3) & 63, n0 = (id >> 9) & 7, kt = id >> 12;
  int k = kt * 32 + (l >> 4) * 8 + j;
  int n = n0 * 16 + (l & 15);
  WpnB[id] = f2b(Wpn[k * 128 + n]);
}

__global__ void k_prep_wgb(const float* Wih, const float* Whh, unsigned short* WgB) {
  int id = blockIdx.x * 256 + threadIdx.x;
  if (id >= 8 * 32 * 64 * 8) return;
  int j = id & 7, l = (id >> 3) & 63, n0 = (id >> 9) & 31, kt = id >> 14;
  int k = kt * 32 + (l >> 4) * 8 + j;
  int jj = n0 * 16 + (l & 15);
  float v = 0.0f;
  if (jj < 256)      v = (k < 128) ? Wih[jj * 128 + k] : Whh[jj * 128 + (k - 128)];
  else if (jj < 384) { if (k < 128)  v = Wih[jj * 128 + k]; }
  else               { if (k >= 128) v = Whh[(jj - 128) * 128 + (k - 128)]; }
  WgB[id] = f2b(v);
}

__global__ void k_prep_wcb(const float* Wc, unsigned short* WcB) {
  int id = blockIdx.x * 256 + threadIdx.x;
  if (id >= 8 * 8 * 64 * 8) return;
  int j = id & 7, l = (id >> 3) & 63, n0 = (id >> 9) & 7, kt = id >> 12;
  int k = kt * 32 + (l >> 4) * 8 + j;
  int n = n0 * 16 + (l & 15);
  WcB[id] = f2b(Wc[k * 128 + n]);
}

// npj = relu(LN(nf @ Wk1 + bk1)) AND pd/ps = nf . We halves.
__global__ void k_npj(const float* nf, const float* Wk1, const float* bk1,
                      const float* g, const float* b, const float* We,
                      float* npj, float* pd, float* ps, int nV) {
  int w = threadIdx.x >> 6, lane = threadIdx.x & 63;
  int v = blockIdx.x * 4 + w;
  if (v >= nV) v = nV - 1;
  __shared__ float x[4][128];
  __shared__ float y[4][20];
  __shared__ float st[4][2];
  float x0 = nf[v * 128 + lane];
  float x1 = nf[v * 128 + 64 + lane];
  x[w][lane]      = x0;
  x[w][lane + 64] = x1;
  float p0 = x0 * We[lane]       + x1 * We[64 + lane];
  float p1 = x0 * We[128 + lane] + x1 * We[192 + lane];
  for (int off = 32; off > 0; off >>= 1) {
    p0 += __shfl_down(p0, off, 64);
    p1 += __shfl_down(p1, off, 64);
  }
  if (lane == 0) { pd[v] = p0; ps[v] = p1; }
  __syncthreads();
  if (lane < G_KP) {
    float acc = bk1[lane];
    for (int t = 0; t < 128; ++t) acc += x[w][t] * Wk1[t * G_KP + lane];
    y[w][lane] = acc;
  }
  __syncthreads();
  if (lane == 0) {
    float s = 0.0f, ss = 0.0f;
    for (int i = 0; i < G_KP; ++i) { s += y[w][i]; ss += y[w][i] * y[w][i]; }
    float mu = s * (1.0f / G_KP);
    float var = ss * (1.0f / G_KP) - mu * mu;
    st[w][0] = mu;
    st[w][1] = rsqrtf(fmaxf(var, 0.0f) + G_LN_EPS);
  }
  __syncthreads();
  if (lane < G_KP) {
    float val = (y[w][lane] - st[w][0]) * st[w][1] * g[lane] + b[lane];
    npj[v * G_KP + lane] = fmaxf(val, 0.0f);
  }
}

// deg histogram
__global__ void k_hist(const int* dst, int* deg, int nE) {
  int e = blockIdx.x * 256 + threadIdx.x;
  if (e < nE) atomicAdd(&deg[dst[e]], 1);
}

// ---- parallel 3-kernel exclusive scan of deg -> rowptr/cursor ----
__global__ void k_scan1(const int* deg, int* bsum, int nV) {
  __shared__ int red[256];
  int b = blockIdx.x, t = threadIdx.x;
  int base = b * 2048 + t * 8;
  int s = 0;
  #pragma unroll
  for (int k = 0; k < 8; ++k) {
    int i = base + k;
    if (i < nV) s += deg[i];
  }
  red[t] = s;
  __syncthreads();
  for (int off = 128; off > 0; off >>= 1) {
    if (t < off) red[t] += red[t + off];
    __syncthreads();
  }
  if (t == 0) bsum[b] = red[0];
}

__global__ void k_scan2(const int* bsum, int* boff, int* total, int nB) {
  __shared__ int sh[1024];
  int t = threadIdx.x;
  int v = (t < nB) ? bsum[t] : 0;
  sh[t] = v;
  __syncthreads();
  for (int off = 1; off < 1024; off <<= 1) {
    int u = (t >= off) ? sh[t - off] : 0;
    __syncthreads();
    sh[t] += u;
    __syncthreads();
  }
  if (t < nB) boff[t] = sh[t] - v;
  if (t == 1023) total[0] = sh[1023];
}

__global__ void k_scan3(const int* deg, const int* boff, const int* total,
                        int* rowptr, int* cursor, int nV) {
  __shared__ int sh[256];
  int b = blockIdx.x, t = threadIdx.x;
  int base = b * 2048 + t * 8;
  int loc[8];
  int s = 0;
  #pragma unroll
  for (int k = 0; k < 8; ++k) {
    int i = base + k;
    int d = (i < nV) ? deg[i] : 0;
    loc[k] = s; s += d;
  }
  sh[t] = s;
  __syncthreads();
  for (int off = 1; off < 256; off <<= 1) {
    int u = (t >= off) ? sh[t - off] : 0;
    __syncthreads();
    sh[t] += u;
    __syncthreads();
  }
  int toff = sh[t] - s + boff[b];
  #pragma unroll
  for (int k = 0; k < 8; ++k) {
    int i = base + k;
    if (i < nV) { rowptr[i] = toff + loc[k]; cursor[i] = toff + loc[k]; }
  }
  if (b == 0 && t == 0) rowptr[nV] = total[0];
}

// per edge: a[e] = exp(min(relu(pd[dst]+ps[src]+be),60)); scatter e into CSR
__global__ void k_edge(const int* src, const int* dst, const float* pd,
                       const float* ps, const float* be, float* a,
                       int* cursor, int* eid, int nE) {
  int e = blockIdx.x * 256 + threadIdx.x;
  if (e >= nE) return;
  int d = dst[e], s_ = src[e];
  float lg = fmaxf(pd[d] + ps[s_] + be[0], 0.0f);
  a[e] = __expf(fminf(lg, 60.0f));
  int pos = atomicAdd(&cursor[d], 1);
  eid[pos] = e;
}

// dst-parallel context gather: wave per node, zero atomics, single pass.
__global__ void k_ctx_gather(const int* rowptr, const int* eid, const int* src,
                             const float* a, const float* nf, float* wctx,
                             int nV) {
  int w = threadIdx.x >> 6, l = threadIdx.x & 63;
  int v = blockIdx.x * 4 + w;
  if (v >= nV) return;
  int beg = rowptr[v], end = rowptr[v + 1];
  float s = 1e-20f, a0 = 0.0f, a1 = 0.0f;
  for (int i = beg; i < end; ++i) {
    int e = eid[i];
    float av = a[e];
    int sn = src[e];
    s  += av;
    a0 += av * nf[sn * 128 + l];
    a1 += av * nf[sn * 128 + 64 + l];
  }
  float dn = 1.0f / s;
  wctx[v * 128 + l]      = a0 * dn;
  wctx[v * 128 + 64 + l] = a1 * dn;
}

// kron branch MFMA (unchanged from R22).
__global__ void __launch_bounds__(256, 4)
k_kron_mfma(const int* src, const int* dst, const float* npj,
            const int* rowptr, const int* eid,
            const unsigned short* Wk2b, const float* bk2,
            const float* g, const float* b, float* kf, int nE) {
  __shared__ unsigned short A_lds[32 * 424];
  __shared__ int eidx[32][2];
  __shared__ unsigned short SDB[4096];
  __shared__ float psq[2][2][16][2];
  unsigned short (*sd)[40] = (unsigned short(*)[40])SDB;
  v8s* B_lds = (v8s*)SDB;
  float* Yf = (float*)A_lds;

  int t = threadIdx.x;
  int w = t >> 6, l = t & 63;
  int c15 = l & 15, quad = l >> 4;
  int pg = w >> 1, hf = w & 1;
  int erbase = pg * 16;

  int ebeg = blockIdx.x * 32;
  int ecnt = nE - ebeg; if (ecnt > 32) ecnt = 32;

  if (t < 32) {
    int e = eid[(t < ecnt) ? (ebeg + t) : ebeg];
    eidx[t][0] = src[e];
    eidx[t][1] = dst[e];
  }
  __syncthreads();
  for (int i = t; i < 1280; i += 256) {
    int er = i / 40, p = i - er * 40;
    float v = (p < 20) ? npj[eidx[er][0] * G_KP + p]
                       : npj[eidx[er][1] * G_KP + (p - 20)];
    sd[er][p] = f2b(v);
  }
  __syncthreads();
  for (int i = t; i < 32 * 16; i += 256) {
    int e = i >> 4, kk = 400 + (i & 15);
    A_lds[e * 424 + kk] = 0;
  }
  {
    int e = t >> 3, l8 = t & 7;
    unsigned int dpk[10];
    #pragma unroll
    for (int m = 0; m < 10; ++m)
      dpk[m] = *(const unsigned int*)&sd[e][20 + 2 * m];
    #pragma unroll
    for (int rr = 0; rr < 3; ++rr) {
      int r = l8 + rr * 8;
      if (r < 20) {
        float s = b2f(sd[e][r]);
        unsigned int* dstp = (unsigned int*)&A_lds[e * 424 + r * 20];
        #pragma unroll
        for (int m = 0; m < 10; ++m) {
          float d0 = bits2f(dpk[m] << 16);
          float d1 = bits2f(dpk[m] & 0xFFFF0000u);
          dstp[m] = cvtpk(s * d0, s * d1);
        }
      }
    }
  }

  v4f acc[4];
  #pragma unroll
  for (int n0 = 0; n0 < 4; ++n0)
    #pragma unroll
    for (int r = 0; r < 4; ++r) acc[n0][r] = 0.0f;

  stage_mfma2<13, 8, 4>((const v8s*)Wk2b, 8, B_lds,
                        &A_lds[(erbase + c15) * 424], 32, quad * 8,
                        hf * 256, t, l, acc);

  float biasv[4], gv[4], bv[4];
  #pragma unroll
  for (int n0 = 0; n0 < 4; ++n0) {
    int n = hf * 64 + n0 * 16 + c15;
    biasv[n0] = bk2[n]; gv[n0] = g[n]; bv[n0] = b[n];
  }
  float sArr[4], qArr[4];
  #pragma unroll
  for (int r = 0; r < 4; ++r) {
    float s = 0.0f, q = 0.0f;
    #pragma unroll
    for (int n0 = 0; n0 < 4; ++n0) {
      float v = acc[n0][r] + biasv[n0];
      s += v; q += v * v;
    }
    for (int m = 1; m < 16; m <<= 1) {
      s += __shfl_xor(s, m, 64);
      q += __shfl_xor(q, m, 64);
    }
    sArr[r] = s; qArr[r] = q;
    if (c15 == 0) {
      psq[pg][hf][quad * 4 + r][0] = s;
      psq[pg][hf][quad * 4 + r][1] = q;
    }
  }
  __syncthreads();
  float mu[4], rs[4];
  #pragma unroll
  for (int r = 0; r < 4; ++r) {
    float s = sArr[r] + psq[pg][hf ^ 1][quad * 4 + r][0];
    float q = qArr[r] + psq[pg][hf ^ 1][quad * 4 + r][1];
    float mm = s * (1.0f / 128.0f);
    float vv = q * (1.0f / 128.0f) - mm * mm;
    mu[r] = mm;
    rs[r] = rsqrtf(fmaxf(vv, 0.0f) + G_LN_EPS);
  }
  #pragma unroll
  for (int r = 0; r < 4; ++r) {
    int eloc = erbase + quad * 4 + r;
    #pragma unroll
    for (int n0 = 0; n0 < 4; ++n0) {
      float v = acc[n0][r] + biasv[n0];
      Yf[eloc * 132 + hf * 64 + n0 * 16 + c15] =
          fmaxf((v - mu[r]) * rs[r] * gv[n0] + bv[n0], 0.0f);
    }
  }
  __syncthreads();

  int dF = eidx[0][1];
  int dL = eidx[ecnt - 1][1];
  int col = t & 127;
  int wend = ebeg + ecnt;
  for (int d = dF + (t >> 7); d <= dL; d += 2) {
    int rb = rowptr[d], re = rowptr[d + 1];
    int lo = (rb > ebeg ? rb : ebeg) - ebeg;
    int hi = (re < wend ? re : wend) - ebeg;
    if (lo >= hi) continue;
    float s = 0.0f;
    for (int i = lo; i < hi; ++i) s += Yf[i * 132 + col];
    if (rb >= ebeg && re <= wend)
      kf[(size_t)d * 128 + col] = s;
    else
      atomicAdd(&kf[(size_t)d * 128 + col], s);
  }
}

// GRU + final. Stage-2 gates in 4 passes of N=128 (acc[8]) with packed bf16
// carries (rr/zz/gi) -> 32 AGPR, 3 blocks/CU.
__global__ void __launch_bounds__(256, 3)
k_gru_mfma(const float* nf, const float* wctx, const float* kf,
           const unsigned short* WpnB, const float* bpn,
           const unsigned short* WgB,
           const float* b_ih, const float* b_hh,
           const float* g1, const float* b1,
           const unsigned short* WcB, const float* bc,
           const float* g2, const float* b2, float* out,
           int nV) {
  __shared__ unsigned short CX[64][264];
  __shared__ v8s B_lds[512];   // 8KB slab (NT=8)
  int t = threadIdx.x;
  int w = t >> 6, l = t & 63;
  int c15 = l & 15, quad = l >> 4;
  int v0 = blockIdx.x * 64;
  int rowbase = w * 16;

  #pragma unroll
  for (int k = 0; k < 8; ++k) {
    int i = l + k * 64;
    int r = i >> 5;
    int seg = i & 31;
    int vn = v0 + rowbase + r; if (vn >= nV) vn = nV - 1;
    v4f wc = *(const v4f*)&wctx[vn * 128 + seg * 4];
    v4f xf = *(const v4f*)&nf[vn * 128 + seg * 4];
    v4s pw = { (short)f2b(wc[0]), (short)f2b(wc[1]), (short)f2b(wc[2]), (short)f2b(wc[3]) };
    v4s px = { (short)f2b(xf[0]), (short)f2b(xf[1]), (short)f2b(xf[2]), (short)f2b(xf[3]) };
    *(v4s*)&CX[rowbase + r][seg * 4]       = pw;
    *(v4s*)&CX[rowbase + r][128 + seg * 4] = px;
  }

  // ---- stage 1: cx = relu(wctx @ Wpn + bpn) ----
  {
    v4f acc[8];
    #pragma unroll
    for (int n0 = 0; n0 < 8; ++n0)
      #pragma unroll
      for (int r = 0; r < 4; ++r) acc[n0][r] = 0.0f;
    stage_mfma2<4, 8, 8>((const v8s*)WpnB, 8, B_lds,
                         &CX[rowbase + c15][0], 32, quad * 8, 0, t, l, acc);
    #pragma unroll
    for (int n0 = 0; n0 < 8; ++n0) {
      int n = n0 * 16 + c15;
      float bo = bpn[n];
      #pragma unroll
      for (int r = 0; r < 4; ++r)
        CX[rowbase + quad * 4 + r][n] = f2b(fmaxf(acc[n0][r] + bo, 0.0f));
    }
  }

  // ---- stage 2: gates, 4 passes of 8 N-tiles each ----
  unsigned int rrp[16], zzp[16], gip[16];
  // pass 1: r preacts (tiles 0..7)
  {
    v4f acc[8];
    #pragma unroll
    for (int n0 = 0; n0 < 8; ++n0)
      #pragma unroll
      for (int r = 0; r < 4; ++r) acc[n0][r] = 0.0f;
    stage_mfma2<8, 8, 8>((const v8s*)WgB, 32, B_lds,
                         &CX[rowbase + c15][0], 32, quad * 8, 0, t, l, acc);
    #pragma unroll
    for (int n0 = 0; n0 < 8; ++n0) {
      int j = n0 * 16 + c15;
      float bb = b_ih[j] + b_hh[j];
      rrp[n0 * 2]     = cvtpk(sigm(acc[n0][0] + bb), sigm(acc[n0][1] + bb));
      rrp[n0 * 2 + 1] = cvtpk(sigm(acc[n0][2] + bb), sigm(acc[n0][3] + bb));
    }
  }
  // pass 2: z preacts (tiles 8..15)
  {
    v4f acc[8];
    #pragma unroll
    for (int n0 = 0; n0 < 8; ++n0)
      #pragma unroll
      for (int r = 0; r < 4; ++r) acc[n0][r] = 0.0f;
    stage_mfma2<8, 8, 8>((const v8s*)WgB + 8 * 64, 32, B_lds,
                         &CX[rowbase + c15][0], 32, quad * 8, 0, t, l, acc);
    #pragma unroll
    for (int n0 = 0; n0 < 8; ++n0) {
      int j = n0 * 16 + c15;
      float bb = b_ih[128 + j] + b_hh[128 + j];
      zzp[n0 * 2]     = cvtpk(sigm(acc[n0][0] + bb), sigm(acc[n0][1] + bb));
      zzp[n0 * 2 + 1] = cvtpk(sigm(acc[n0][2] + bb), sigm(acc[n0][3] + bb));
    }
  }
  // pass 3: gi_n (tiles 16..23)
  {
    v4f acc[8];
    #pragma unroll
    for (int n0 = 0; n0 < 8; ++n0)
      #pragma unroll
      for (int r = 0; r < 4; ++r) acc[n0][r] = 0.0f;
    stage_mfma2<8, 8, 8>((const v8s*)WgB + 16 * 64, 32, B_lds,
                         &CX[rowbase + c15][0], 32, quad * 8, 0, t, l, acc);
    #pragma unroll
    for (int n0 = 0; n0 < 8; ++n0) {
      int j = n0 * 16 + c15;
      float bb = b_ih[256 + j];
      gip[n0 * 2]     = cvtpk(acc[n0][0] + bb, acc[n0][1] + bb);
      gip[n0 * 2 + 1] = cvtpk(acc[n0][2] + bb, acc[n0][3] + bb);
    }
  }
  // pass 4: gh_n (tiles 24..31) + GRU + LN
  {
    v4f acc[8];
    #pragma unroll
    for (int n0 = 0; n0 < 8; ++n0)
      #pragma unroll
      for (int r = 0; r < 4; ++r) acc[n0][r] = 0.0f;
    stage_mfma2<8, 8, 8>((const v8s*)WgB + 24 * 64, 32, B_lds,
                         &CX[rowbase + c15][0], 32, quad * 8, 0, t, l, acc);
    #pragma unroll
    for (int r = 0; r < 4; ++r) {
      int row = rowbase + quad * 4 + r;
      float h[8];
      float s = 0.0f, q = 0.0f;
      #pragma unroll
      for (int n0 = 0; n0 < 8; ++n0) {
        int j = n0 * 16 + c15;
        float gh = acc[n0][r] + b_hh[256 + j];
        float rr = unpk(rrp[n0 * 2 + (r >> 1)], r & 1);
        float zz = unpk(zzp[n0 * 2 + (r >> 1)], r & 1);
        float gi = unpk(gip[n0 * 2 + (r >> 1)], r & 1);
        float an = fmaxf(fminf(gi + rr * gh, 15.0f), -15.0f);
        float e2 = __expf(-2.0f * an);
        float nn = (1.0f - e2) / (1.0f + e2);
        float x  = b2f(CX[row][128 + j]);
        float hv = fmaxf((1.0f - zz) * nn + zz * x, 0.0f);   // relu BEFORE LN
        h[n0] = hv; s += hv; q += hv * hv;
      }
      for (int m = 1; m < 16; m <<= 1) {
        s += __shfl_xor(s, m, 64);
        q += __shfl_xor(q, m, 64);
      }
      float mu = s * (1.0f / 128.0f);
      float var = q * (1.0f / 128.0f) - mu * mu;
      float rstd = rsqrtf(fmaxf(var, 0.0f) + G_LN_EPS);
      #pragma unroll
      for (int n0 = 0; n0 < 8; ++n0) {
        int j = n0 * 16 + c15;
        CX[row][j] = f2b((h[n0] - mu) * rstd * g1[j] + b1[j]);
      }
    }
  }

  // ---- stage kf ----
  #pragma unroll
  for (int k = 0; k < 8; ++k) {
    int i = l + k * 64;
    int r = i >> 5, seg = i & 31;
    int vn = v0 + rowbase + r; if (vn >= nV) vn = nV - 1;
    v4f kv = *(const v4f*)&kf[vn * 128 + seg * 4];
    v4s pk = { (short)f2b(kv[0]), (short)f2b(kv[1]), (short)f2b(kv[2]), (short)f2b(kv[3]) };
    *(v4s*)&CX[rowbase + r][128 + seg * 4] = pk;
  }

  // ---- stage 3 ----
  {
    v4f acc[8];
    #pragma unroll
    for (int n0 = 0; n0 < 8; ++n0)
      #pragma unroll
      for (int r = 0; r < 4; ++r) acc[n0][r] = 0.0f;
    stage_mfma2<8, 8, 8>((const v8s*)WcB, 8, B_lds,
                         &CX[rowbase + c15][0], 32, quad * 8, 0, t, l, acc);
    #pragma unroll
    for (int r = 0; r < 4; ++r) {
      float vv[8];
      float s = 0.0f, q = 0.0f;
      #pragma unroll
      for (int n0 = 0; n0 < 8; ++n0) {
        vv[n0] = acc[n0][r] + bc[n0 * 16 + c15];
        s += vv[n0]; q += vv[n0] * vv[n0];
      }
      for (int m = 1; m < 16; m <<= 1) {
        s += __shfl_xor(s, m, 64);
        q += __shfl_xor(q, m, 64);
      }
      float mu = s * (1.0f / 128.0f);
      float var = q * (1.0f / 128.0f) - mu * mu;
      float rstd = rsqrtf(fmaxf(var, 0.0f) + G_LN_EPS);
      int vn = v0 + rowbase + quad * 4 + r;
      if (vn < nV) {
        #pragma unroll
        for (int n0 = 0; n0 < 8; ++n0) {
          int n = n0 * 16 + c15;
          float y = fmaxf((vv[n0] - mu) * rstd * g2[n] + b2[n], 0.0f);
          if (y != y) y = 9.0f;   // NaN canary
          out[vn * 128 + n] = y;
        }
      }
    }
  }
}

extern "C" void kernel_launch(void* const* d_in, const int* in_sizes, int n_in,
                              void* d_out, int out_size, void* d_ws, size_t ws_size,
                              hipStream_t stream) {
  (void)n_in;

  int nV = in_sizes[0] / 128;
  int nE = in_sizes[1];

  const float* nf     = (const float*)d_in[0];
  const int*   src    = (const int*)d_in[1];
  const int*   dst    = (const int*)d_in[2];
  const float* W_edge = (const float*)d_in[3];
  const float* b_edge = (const float*)d_in[4];
  const float* W_pn   = (const float*)d_in[5];
  const float* b_pn   = (const float*)d_in[6];
  const float* W_ih   = (const float*)d_in[7];
  const float* b_ih   = (const float*)d_in[8];
  const float* W_hh   = (const float*)d_in[9];
  const float* b_hh   = (const float*)d_in[10];
  const float* ln_g   = (const float*)d_in[11];
  const float* ln_b   = (const float*)d_in[12];
  const float* Wk1    = (const float*)d_in[13];
  const float* bk1    = (const float*)d_in[14];
  const float* lnk1_g = (const float*)d_in[15];
  const float* lnk1_b = (const float*)d_in[16];
  const float* Wk2    = (const float*)d_in[17];
  const float* bk2    = (const float*)d_in[18];
  const float* lnk2_g = (const float*)d_in[19];
  const float* lnk2_b = (const float*)d_in[20];
  const float* Wc     = (const float*)d_in[21];
  const float* bc     = (const float*)d_in[22];
  const float* lnc_g  = (const float*)d_in[23];
  const float* lnc_b  = (const float*)d_in[24];

  float* ws = (float*)d_ws;
  size_t off = 0;
  float* w_npj  = ws + off; off += (size_t)nV * G_KP;
  float* w_a    = ws + off; off += (size_t)nE;
  float* w_pd   = ws + off; off += (size_t)nV;
  float* w_ps   = ws + off; off += (size_t)nV;
  int*   w_rowp = (int*)(ws + off); off += (size_t)nV + 1;
  int*   w_curs = (int*)(ws + off); off += (size_t)nV;
  int*   w_eid  = (int*)(ws + off); off += (size_t)nE;
  int*   w_bsum = (int*)(ws + off); off += 1024;
  int*   w_boff = (int*)(ws + off); off += 1024;
  int*   w_tot  = (int*)(ws + off); off += 1;
  float* w_wctx = ws + off; off += (size_t)nV * 128;
  int*   w_deg  = (int*)(ws + off); off += (size_t)nV;       // zeroed
  float* w_kf   = ws + off; off += (size_t)nV * 128;         // zeroed
  unsigned short* w_wk2b = (unsigned short*)(ws + off); off += 26624;
  unsigned short* w_wpnb = (unsigned short*)(ws + off); off += 8192;
  unsigned short* w_wgb  = (unsigned short*)(ws + off); off += 65536;
  unsigned short* w_wcb  = (unsigned short*)(ws + off); off += 16384;
  size_t need_bytes = off * 4;

  if (ws_size < need_bytes) {   // decodable: absmax ~= 7.0
    k_fill<<<(out_size + 255) / 256, 256, 0, stream>>>((float*)d_out, out_size, 7.0f);
    return;
  }

  // sentinel: mid-pipeline death decodes as absmax ~= 2.97
  k_fill<<<(out_size + 255) / 256, 256, 0, stream>>>((float*)d_out, out_size, 2.0f);

  int nzero = nV * 129;  // deg + kf (contiguous)
  k_zero<<<(nzero + 255) / 256, 256, 0, stream>>>((float*)w_deg, nzero);
  k_prep_wk2b<<<208, 256, 0, stream>>>(Wk2, w_wk2b);
  k_prep_wpnb<<<64, 256, 0, stream>>>(W_pn, w_wpnb);
  k_prep_wgb<<<512, 256, 0, stream>>>(W_ih, W_hh, w_wgb);
  k_prep_wcb<<<128, 256, 0, stream>>>(Wc, w_wcb);

  int nB = (nV + 2047) / 2048;
  k_npj<<<(nV + 3) / 4, 256, 0, stream>>>(nf, Wk1, bk1, lnk1_g, lnk1_b,
                                          W_edge, w_npj, w_pd, w_ps, nV);
  k_hist<<<(nE + 255) / 256, 256, 0, stream>>>(dst, w_deg, nE);
  k_scan1<<<nB, 256, 0, stream>>>(w_deg, w_bsum, nV);
  k_scan2<<<1, 1024, 0, stream>>>(w_bsum, w_boff, w_tot, nB);
  k_scan3<<<nB, 256, 0, stream>>>(w_deg, w_boff, w_tot, w_rowp, w_curs, nV);
  k_edge<<<(nE + 255) / 256, 256, 0, stream>>>(src, dst, w_pd, w_ps, b_edge,
                                               w_a, w_curs, w_eid, nE);
  k_ctx_gather<<<(nV + 3) / 4, 256, 0, stream>>>(w_rowp, w_eid, src, w_a, nf,
                                                 w_wctx, nV);
  k_kron_mfma<<<(nE + 31) / 32, 256, 0, stream>>>(src, dst, w_npj, w_rowp,
                                                  w_eid, w_wk2b, bk2,
                                                  lnk2_g, lnk2_b, w_kf, nE);
  k_gru_mfma<<<(nV + 63) / 64, 256, 0, stream>>>(nf, w_wctx, w_kf, w_wpnb, b_pn,
                                                 w_wgb, b_ih, b_hh, ln_g, ln_b,
                                                 w_wcb, bc, lnc_g, lnc_b,
                                                 (float*)d_out, nV);
}

// Round 14
// 652.858 us; speedup vs baseline: 1.0700x; 1.0700x over previous
//
// R24: gru K-loop re-pipelined: 2-deep register prefetch + double-buffered
// LDS slab + RAW s_barrier (no vmcnt(0) drain). R23 post-mortem: occupancy
// 20->27.7% yet dur unchanged -> within-block serialization; __syncthreads
// drains vmcnt(0) every kt (44x/block) exposing full load latency at
// prefetch depth 1. stage_pipe8: ds_write's operand dep gives a COUNTED
// vmcnt wait for the 2-kt-old load; lgkmcnt(0)+raw barrier for slab
// visibility; sched_barrier(0) pins order (rule #18). kron untouched (A/B).
#include <hip/hip_runtime.h>

#define G_KP 20
#define G_LN_EPS 1e-5f

typedef float v4f __attribute__((ext_vector_type(4)));
typedef short v8s __attribute__((ext_vector_type(8)));
typedef short v4s __attribute__((ext_vector_type(4)));

__device__ __forceinline__ unsigned short f2b(float x) {
  union { float f; unsigned int i; } c;
  c.f = x;
  return (unsigned short)((c.i + 0x7FFFu + ((c.i >> 16) & 1u)) >> 16);
}
__device__ __forceinline__ float b2f(unsigned short u) {
  union { unsigned int i; float f; } c;
  c.i = ((unsigned int)u) << 16;
  return c.f;
}
__device__ __forceinline__ float bits2f(unsigned int i) {
  union { unsigned int i; float f; } c;
  c.i = i;
  return c.f;
}
// 2x f32 -> packed bf16 (RNE): lo -> low16, hi -> high16
__device__ __forceinline__ unsigned int cvtpk(float lo, float hi) {
  unsigned int r;
  asm("v_cvt_pk_bf16_f32 %0, %1, %2" : "=v"(r) : "v"(lo), "v"(hi));
  return r;
}
__device__ __forceinline__ float unpk(unsigned int pk, int odd) {
  return odd ? bits2f(pk & 0xFFFF0000u) : bits2f(pk << 16);
}
__device__ __forceinline__ float sigm(float x) {
  return 1.0f / (1.0f + __expf(-fmaxf(fminf(x, 30.0f), -30.0f)));
}

// Legacy shared-B stage (kron): per-kt cooperative staging with __syncthreads.
template<int NKT, int NTS, int NTU>
__device__ __forceinline__ void stage_mfma2(
    const v8s* __restrict__ Bsrc, int kt_tiles, v8s* B_lds,
    const unsigned short* Arow, int a_kt, int a_off, int b_off,
    int t, int l, v4f* acc) {
  constexpr int NPR = NTS / 4;
  v8s pr[NPR];
  #pragma unroll
  for (int i = 0; i < NPR; ++i) pr[i] = Bsrc[t + i * 256];
  #pragma unroll
  for (int kt = 0; kt < NKT; ++kt) {
    __syncthreads();
    #pragma unroll
    for (int i = 0; i < NPR; ++i) B_lds[t + i * 256] = pr[i];
    if (kt + 1 < NKT) {
      #pragma unroll
      for (int i = 0; i < NPR; ++i)
        pr[i] = Bsrc[(kt + 1) * kt_tiles * 64 + t + i * 256];
    }
    __syncthreads();
    v8s a = *(const v8s*)&Arow[kt * a_kt + a_off];
    #pragma unroll
    for (int n0 = 0; n0 < NTU; ++n0)
      acc[n0] = __builtin_amdgcn_mfma_f32_16x16x32_bf16(a, B_lds[b_off + n0 * 64 + l], acc[n0], 0, 0, 0);
  }
}

// Pipelined shared-B stage (gru): 2-deep reg prefetch, double-buffered slab
// (B2 = 1024 v8s = two 8KB slabs), raw barriers, counted vmcnt via operand
// dependency. All waves uniform barrier count (uniform control flow).
template<int NKT>
__device__ __forceinline__ void stage_pipe8(
    const v8s* __restrict__ Bsrc, int kt_tiles, v8s* B2,
    const unsigned short* Arow, int a_kt, int a_off,
    int t, int l, v4f* acc) {
  v8s ra[2], rb[2];
  #pragma unroll
  for (int i = 0; i < 2; ++i) ra[i] = Bsrc[t + i * 256];
  #pragma unroll
  for (int i = 0; i < 2; ++i)
    rb[i] = (NKT > 1) ? Bsrc[kt_tiles * 64 + t + i * 256] : ra[i];
  #pragma unroll
  for (int kt = 0; kt < NKT; ++kt) {
    __builtin_amdgcn_s_barrier();          // slab[kt&1] free (read 2 kts ago)
    __builtin_amdgcn_sched_barrier(0);
    v8s* slab = B2 + (kt & 1) * 512;
    #pragma unroll
    for (int i = 0; i < 2; ++i)
      slab[t + i * 256] = (kt & 1) ? rb[i] : ra[i];   // counted vmcnt wait here
    if (kt + 2 < NKT) {
      #pragma unroll
      for (int i = 0; i < 2; ++i) {
        v8s v = Bsrc[(kt + 2) * kt_tiles * 64 + t + i * 256];
        if (kt & 1) rb[i] = v; else ra[i] = v;
      }
    }
    asm volatile("s_waitcnt lgkmcnt(0)" ::: "memory");  // our ds_writes done
    __builtin_amdgcn_s_barrier();          // slab visible to all waves
    __builtin_amdgcn_sched_barrier(0);
    v8s a = *(const v8s*)&Arow[kt * a_kt + a_off];
    #pragma unroll
    for (int n0 = 0; n0 < 8; ++n0)
      acc[n0] = __builtin_amdgcn_mfma_f32_16x16x32_bf16(a, slab[n0 * 64 + l], acc[n0], 0, 0, 0);
  }
}

// original stub symbol (kept; harmless)
__global__ void GNNLayerKAFP_76871324663923_kernel() {}

__global__ void k_fill(float* out, int n, float v) {
  int i = blockIdx.x * 256 + threadIdx.x;
  if (i < n) out[i] = v;
}

__global__ void k_zero(float* p, int n) {
  int i = blockIdx.x * 256 + threadIdx.x;
  if (i < n) p[i] = 0.0f;
}

// ---- B-fragment packers (unchanged) ----
__global__ void k_prep_wk2b(const float* Wk2, unsigned short* Wk2b) {
  int id = blockIdx.x * 256 + threadIdx.x;
  if (id >= 13 * 8 * 64 * 8) return;
  int j = id & 7, l = (id >> 3) & 63, n0 = (id >> 9) & 7, kt = id >> 12;
  int k = kt * 32 + (l >> 4) * 8 + j;
  int n = n0 * 16 + (l & 15);
  Wk2b[id] = f2b((k < 400) ? Wk2[k * 128 + n] : 0.0f);
}

__global__ void k_prep_wpnb(const float* Wpn, unsigned short* WpnB) {
  int id = blockIdx.x * 256 + threadIdx.x;
  if (id >= 4 * 8 * 64 * 8) return;
  int j = id & 7, l = (id >> 3) & 63, n0 = (id >> 9) & 7, kt = id >> 12;
  int k = kt * 32 + (l >> 4) * 8 + j;
  int n = n0 * 16 + (l & 15);
  WpnB[id] = f2b(Wpn[k * 128 + n]);
}

__global__ void k_prep_wgb(const float* Wih, const float* Whh, unsigned short* WgB) {
  int id = blockIdx.x * 256 + threadIdx.x;
  if (id >= 8 * 32 * 64 * 8) return;
  int j = id & 7, l = (id >> 3) & 63, n0 = (id >> 9) & 31, kt = id >> 14;
  int k = kt * 32 + (l >> 4) * 8 + j;
  int jj = n0 * 16 + (l & 15);
  float v = 0.0f;
  if (jj < 256)      v = (k < 128) ? Wih[jj * 128 + k] : Whh[jj * 128 + (k - 128)];
  else if (jj < 384) { if (k < 128)  v = Wih[jj * 128 + k]; }
  else               { if (k >= 128) v = Whh[(jj - 128) * 128 + (k - 128)]; }
  WgB[id] = f2b(v);
}

__global__ void k_prep_wcb(const float* Wc, unsigned short* WcB) {
  int id = blockIdx.x * 256 + threadIdx.x;
  if (id >= 8 * 8 * 64 * 8) return;
  int j = id & 7, l = (id >> 3) & 63, n0 = (id >> 9) & 7, kt = id >> 12;
  int k = kt * 32 + (l >> 4) * 8 + j;
  int n = n0 * 16 + (l & 15);
  WcB[id] = f2b(Wc[k * 128 + n]);
}

// npj = relu(LN(nf @ Wk1 + bk1)) AND pd/ps = nf . We halves.
__global__ void k_npj(const float* nf, const float* Wk1, const float* bk1,
                      const float* g, const float* b, const float* We,
                      float* npj, float* pd, float* ps, int nV) {
  int w = threadIdx.x >> 6, lane = threadIdx.x & 63;
  int v = blockIdx.x * 4 + w;
  if (v >= nV) v = nV - 1;
  __shared__ float x[4][128];
  __shared__ float y[4][20];
  __shared__ float st[4][2];
  float x0 = nf[v * 128 + lane];
  float x1 = nf[v * 128 + 64 + lane];
  x[w][lane]      = x0;
  x[w][lane + 64] = x1;
  float p0 = x0 * We[lane]       + x1 * We[64 + lane];
  float p1 = x0 * We[128 + lane] + x1 * We[192 + lane];
  for (int off = 32; off > 0; off >>= 1) {
    p0 += __shfl_down(p0, off, 64);
    p1 += __shfl_down(p1, off, 64);
  }
  if (lane == 0) { pd[v] = p0; ps[v] = p1; }
  __syncthreads();
  if (lane < G_KP) {
    float acc = bk1[lane];
    for (int t = 0; t < 128; ++t) acc += x[w][t] * Wk1[t * G_KP + lane];
    y[w][lane] = acc;
  }
  __syncthreads();
  if (lane == 0) {
    float s = 0.0f, ss = 0.0f;
    for (int i = 0; i < G_KP; ++i) { s += y[w][i]; ss += y[w][i] * y[w][i]; }
    float mu = s * (1.0f / G_KP);
    float var = ss * (1.0f / G_KP) - mu * mu;
    st[w][0] = mu;
    st[w][1] = rsqrtf(fmaxf(var, 0.0f) + G_LN_EPS);
  }
  __syncthreads();
  if (lane < G_KP) {
    float val = (y[w][lane] - st[w][0]) * st[w][1] * g[lane] + b[lane];
    npj[v * G_KP + lane] = fmaxf(val, 0.0f);
  }
}

// deg histogram
__global__ void k_hist(const int* dst, int* deg, int nE) {
  int e = blockIdx.x * 256 + threadIdx.x;
  if (e < nE) atomicAdd(&deg[dst[e]], 1);
}

// ---- parallel 3-kernel exclusive scan of deg -> rowptr/cursor ----
__global__ void k_scan1(const int* deg, int* bsum, int nV) {
  __shared__ int red[256];
  int b = blockIdx.x, t = threadIdx.x;
  int base = b * 2048 + t * 8;
  int s = 0;
  #pragma unroll
  for (int k = 0; k < 8; ++k) {
    int i = base + k;
    if (i < nV) s += deg[i];
  }
  red[t] = s;
  __syncthreads();
  for (int off = 128; off > 0; off >>= 1) {
    if (t < off) red[t] += red[t + off];
    __syncthreads();
  }
  if (t == 0) bsum[b] = red[0];
}

__global__ void k_scan2(const int* bsum, int* boff, int* total, int nB) {
  __shared__ int sh[1024];
  int t = threadIdx.x;
  int v = (t < nB) ? bsum[t] : 0;
  sh[t] = v;
  __syncthreads();
  for (int off = 1; off < 1024; off <<= 1) {
    int u = (t >= off) ? sh[t - off] : 0;
    __syncthreads();
    sh[t] += u;
    __syncthreads();
  }
  if (t < nB) boff[t] = sh[t] - v;
  if (t == 1023) total[0] = sh[1023];
}

__global__ void k_scan3(const int* deg, const int* boff, const int* total,
                        int* rowptr, int* cursor, int nV) {
  __shared__ int sh[256];
  int b = blockIdx.x, t = threadIdx.x;
  int base = b * 2048 + t * 8;
  int loc[8];
  int s = 0;
  #pragma unroll
  for (int k = 0; k < 8; ++k) {
    int i = base + k;
    int d = (i < nV) ? deg[i] : 0;
    loc[k] = s; s += d;
  }
  sh[t] = s;
  __syncthreads();
  for (int off = 1; off < 256; off <<= 1) {
    int u = (t >= off) ? sh[t - off] : 0;
    __syncthreads();
    sh[t] += u;
    __syncthreads();
  }
  int toff = sh[t] - s + boff[b];
  #pragma unroll
  for (int k = 0; k < 8; ++k) {
    int i = base + k;
    if (i < nV) { rowptr[i] = toff + loc[k]; cursor[i] = toff + loc[k]; }
  }
  if (b == 0 && t == 0) rowptr[nV] = total[0];
}

// per edge: a[e] = exp(min(relu(pd[dst]+ps[src]+be),60)); scatter e into CSR
__global__ void k_edge(const int* src, const int* dst, const float* pd,
                       const float* ps, const float* be, float* a,
                       int* cursor, int* eid, int nE) {
  int e = blockIdx.x * 256 + threadIdx.x;
  if (e >= nE) return;
  int d = dst[e], s_ = src[e];
  float lg = fmaxf(pd[d] + ps[s_] + be[0], 0.0f);
  a[e] = __expf(fminf(lg, 60.0f));
  int pos = atomicAdd(&cursor[d], 1);
  eid[pos] = e;
}

// dst-parallel context gather: wave per node, zero atomics, single pass.
__global__ void k_ctx_gather(const int* rowptr, const int* eid, const int* src,
                             const float* a, const float* nf, float* wctx,
                             int nV) {
  int w = threadIdx.x >> 6, l = threadIdx.x & 63;
  int v = blockIdx.x * 4 + w;
  if (v >= nV) return;
  int beg = rowptr[v], end = rowptr[v + 1];
  float s = 1e-20f, a0 = 0.0f, a1 = 0.0f;
  for (int i = beg; i < end; ++i) {
    int e = eid[i];
    float av = a[e];
    int sn = src[e];
    s  += av;
    a0 += av * nf[sn * 128 + l];
    a1 += av * nf[sn * 128 + 64 + l];
  }
  float dn = 1.0f / s;
  wctx[v * 128 + l]      = a0 * dn;
  wctx[v * 128 + 64 + l] = a1 * dn;
}

// kron branch MFMA (unchanged from R22/R23).
__global__ void __launch_bounds__(256, 4)
k_kron_mfma(const int* src, const int* dst, const float* npj,
            const int* rowptr, const int* eid,
            const unsigned short* Wk2b, const float* bk2,
            const float* g, const float* b, float* kf, int nE) {
  __shared__ unsigned short A_lds[32 * 424];
  __shared__ int eidx[32][2];
  __shared__ unsigned short SDB[4096];
  __shared__ float psq[2][2][16][2];
  unsigned short (*sd)[40] = (unsigned short(*)[40])SDB;
  v8s* B_lds = (v8s*)SDB;
  float* Yf = (float*)A_lds;

  int t = threadIdx.x;
  int w = t >> 6, l = t & 63;
  int c15 = l & 15, quad = l >> 4;
  int pg = w >> 1, hf = w & 1;
  int erbase = pg * 16;

  int ebeg = blockIdx.x * 32;
  int ecnt = nE - ebeg; if (ecnt > 32) ecnt = 32;

  if (t < 32) {
    int e = eid[(t < ecnt) ? (ebeg + t) : ebeg];
    eidx[t][0] = src[e];
    eidx[t][1] = dst[e];
  }
  __syncthreads();
  for (int i = t; i < 1280; i += 256) {
    int er = i / 40, p = i - er * 40;
    float v = (p < 20) ? npj[eidx[er][0] * G_KP + p]
                       : npj[eidx[er][1] * G_KP + (p - 20)];
    sd[er][p] = f2b(v);
  }
  __syncthreads();
  for (int i = t; i < 32 * 16; i += 256) {
    int e = i >> 4, kk = 400 + (i & 15);
    A_lds[e * 424 + kk] = 0;
  }
  {
    int e = t >> 3, l8 = t & 7;
    unsigned int dpk[10];
    #pragma unroll
    for (int m = 0; m < 10; ++m)
      dpk[m] = *(const unsigned int*)&sd[e][20 + 2 * m];
    #pragma unroll
    for (int rr = 0; rr < 3; ++rr) {
      int r = l8 + rr * 8;
      if (r < 20) {
        float s = b2f(sd[e][r]);
        unsigned int* dstp = (unsigned int*)&A_lds[e * 424 + r * 20];
        #pragma unroll
        for (int m = 0; m < 10; ++m) {
          float d0 = bits2f(dpk[m] << 16);
          float d1 = bits2f(dpk[m] & 0xFFFF0000u);
          dstp[m] = cvtpk(s * d0, s * d1);
        }
      }
    }
  }

  v4f acc[4];
  #pragma unroll
  for (int n0 = 0; n0 < 4; ++n0)
    #pragma unroll
    for (int r = 0; r < 4; ++r) acc[n0][r] = 0.0f;

  stage_mfma2<13, 8, 4>((const v8s*)Wk2b, 8, B_lds,
                        &A_lds[(erbase + c15) * 424], 32, quad * 8,
                        hf * 256, t, l, acc);

  float biasv[4], gv[4], bv[4];
  #pragma unroll
  for (int n0 = 0; n0 < 4; ++n0) {
    int n = hf * 64 + n0 * 16 + c15;
    biasv[n0] = bk2[n]; gv[n0] = g[n]; bv[n0] = b[n];
  }
  float sArr[4], qArr[4];
  #pragma unroll
  for (int r = 0; r < 4; ++r) {
    float s = 0.0f, q = 0.0f;
    #pragma unroll
    for (int n0 = 0; n0 < 4; ++n0) {
      float v = acc[n0][r] + biasv[n0];
      s += v; q += v * v;
    }
    for (int m = 1; m < 16; m <<= 1) {
      s += __shfl_xor(s, m, 64);
      q += __shfl_xor(q, m, 64);
    }
    sArr[r] = s; qArr[r] = q;
    if (c15 == 0) {
      psq[pg][hf][quad * 4 + r][0] = s;
      psq[pg][hf][quad * 4 + r][1] = q;
    }
  }
  __syncthreads();
  float mu[4], rs[4];
  #pragma unroll
  for (int r = 0; r < 4; ++r) {
    float s = sArr[r] + psq[pg][hf ^ 1][quad * 4 + r][0];
    float q = qArr[r] + psq[pg][hf ^ 1][quad * 4 + r][1];
    float mm = s * (1.0f / 128.0f);
    float vv = q * (1.0f / 128.0f) - mm * mm;
    mu[r] = mm;
    rs[r] = rsqrtf(fmaxf(vv, 0.0f) + G_LN_EPS);
  }
  #pragma unroll
  for (int r = 0; r < 4; ++r) {
    int eloc = erbase + quad * 4 + r;
    #pragma unroll
    for (int n0 = 0; n0 < 4; ++n0) {
      float v = acc[n0][r] + biasv[n0];
      Yf[eloc * 132 + hf * 64 + n0 * 16 + c15] =
          fmaxf((v - mu[r]) * rs[r] * gv[n0] + bv[n0], 0.0f);
    }
  }
  __syncthreads();

  int dF = eidx[0][1];
  int dL = eidx[ecnt - 1][1];
  int col = t & 127;
  int wend = ebeg + ecnt;
  for (int d = dF + (t >> 7); d <= dL; d += 2) {
    int rb = rowptr[d], re = rowptr[d + 1];
    int lo = (rb > ebeg ? rb : ebeg) - ebeg;
    int hi = (re < wend ? re : wend) - ebeg;
    if (lo >= hi) continue;
    float s = 0.0f;
    for (int i = lo; i < hi; ++i) s += Yf[i * 132 + col];
    if (rb >= ebeg && re <= wend)
      kf[(size_t)d * 128 + col] = s;
    else
      atomicAdd(&kf[(size_t)d * 128 + col], s);
  }
}

// GRU + final: stage_pipe8 K-loops (raw barriers, 2-deep prefetch).
__global__ void __launch_bounds__(256, 3)
k_gru_mfma(const float* nf, const float* wctx, const float* kf,
           const unsigned short* WpnB, const float* bpn,
           const unsigned short* WgB,
           const float* b_ih, const float* b_hh,
           const float* g1, const float* b1,
           const unsigned short* WcB, const float* bc,
           const float* g2, const float* b2, float* out,
           int nV) {
  __shared__ unsigned short CX[64][264];
  __shared__ v8s B2[1024];   // two 8KB slabs
  int t = threadIdx.x;
  int w = t >> 6, l = t & 63;
  int c15 = l & 15, quad = l >> 4;
  int v0 = blockIdx.x * 64;
  int rowbase = w * 16;

  #pragma unroll
  for (int k = 0; k < 8; ++k) {
    int i = l + k * 64;
    int r = i >> 5;
    int seg = i & 31;
    int vn = v0 + rowbase + r; if (vn >= nV) vn = nV - 1;
    v4f wc = *(const v4f*)&wctx[vn * 128 + seg * 4];
    v4f xf = *(const v4f*)&nf[vn * 128 + seg * 4];
    v4s pw = { (short)f2b(wc[0]), (short)f2b(wc[1]), (short)f2b(wc[2]), (short)f2b(wc[3]) };
    v4s px = { (short)f2b(xf[0]), (short)f2b(xf[1]), (short)f2b(xf[2]), (short)f2b(xf[3]) };
    *(v4s*)&CX[rowbase + r][seg * 4]       = pw;
    *(v4s*)&CX[rowbase + r][128 + seg * 4] = px;
  }

  // ---- stage 1: cx = relu(wctx @ Wpn + bpn) ----
  {
    v4f acc[8];
    #pragma unroll
    for (int n0 = 0; n0 < 8; ++n0)
      #pragma unroll
      for (int r = 0; r < 4; ++r) acc[n0][r] = 0.0f;
    stage_pipe8<4>((const v8s*)WpnB, 8, B2,
                   &CX[rowbase + c15][0], 32, quad * 8, t, l, acc);
    #pragma unroll
    for (int n0 = 0; n0 < 8; ++n0) {
      int n = n0 * 16 + c15;
      float bo = bpn[n];
      #pragma unroll
      for (int r = 0; r < 4; ++r)
        CX[rowbase + quad * 4 + r][n] = f2b(fmaxf(acc[n0][r] + bo, 0.0f));
    }
  }

  // ---- stage 2: gates, 4 passes of 8 N-tiles each ----
  unsigned int rrp[16], zzp[16], gip[16];
  // pass 1: r preacts (tiles 0..7)
  {
    v4f acc[8];
    #pragma unroll
    for (int n0 = 0; n0 < 8; ++n0)
      #pragma unroll
      for (int r = 0; r < 4; ++r) acc[n0][r] = 0.0f;
    stage_pipe8<8>((const v8s*)WgB, 32, B2,
                   &CX[rowbase + c15][0], 32, quad * 8, t, l, acc);
    #pragma unroll
    for (int n0 = 0; n0 < 8; ++n0) {
      int j = n0 * 16 + c15;
      float bb = b_ih[j] + b_hh[j];
      rrp[n0 * 2]     = cvtpk(sigm(acc[n0][0] + bb), sigm(acc[n0][1] + bb));
      rrp[n0 * 2 + 1] = cvtpk(sigm(acc[n0][2] + bb), sigm(acc[n0][3] + bb));
    }
  }
  // pass 2: z preacts (tiles 8..15)
  {
    v4f acc[8];
    #pragma unroll
    for (int n0 = 0; n0 < 8; ++n0)
      #pragma unroll
      for (int r = 0; r < 4; ++r) acc[n0][r] = 0.0f;
    stage_pipe8<8>((const v8s*)WgB + 8 * 64, 32, B2,
                   &CX[rowbase + c15][0], 32, quad * 8, t, l, acc);
    #pragma unroll
    for (int n0 = 0; n0 < 8; ++n0) {
      int j = n0 * 16 + c15;
      float bb = b_ih[128 + j] + b_hh[128 + j];
      zzp[n0 * 2]     = cvtpk(sigm(acc[n0][0] + bb), sigm(acc[n0][1] + bb));
      zzp[n0 * 2 + 1] = cvtpk(sigm(acc[n0][2] + bb), sigm(acc[n0][3] + bb));
    }
  }
  // pass 3: gi_n (tiles 16..23)
  {
    v4f acc[8];
    #pragma unroll
    for (int n0 = 0; n0 < 8; ++n0)
      #pragma unroll
      for (int r = 0; r < 4; ++r) acc[n0][r] = 0.0f;
    stage_pipe8<8>((const v8s*)WgB + 16 * 64, 32, B2,
                   &CX[rowbase + c15][0], 32, quad * 8, t, l, acc);
    #pragma unroll
    for (int n0 = 0; n0 < 8; ++n0) {
      int j = n0 * 16 + c15;
      float bb = b_ih[256 + j];
      gip[n0 * 2]     = cvtpk(acc[n0][0] + bb, acc[n0][1] + bb);
      gip[n0 * 2 + 1] = cvtpk(acc[n0][2] + bb, acc[n0][3] + bb);
    }
  }
  // pass 4: gh_n (tiles 24..31) + GRU + LN
  {
    v4f acc[8];
    #pragma unroll
    for (int n0 = 0; n0 < 8; ++n0)
      #pragma unroll
      for (int r = 0; r < 4; ++r) acc[n0][r] = 0.0f;
    stage_pipe8<8>((const v8s*)WgB + 24 * 64, 32, B2,
                   &CX[rowbase + c15][0], 32, quad * 8, t, l, acc);
    #pragma unroll
    for (int r = 0; r < 4; ++r) {
      int row = rowbase + quad * 4 + r;
      float h[8];
      float s = 0.0f, q = 0.0f;
      #pragma unroll
      for (int n0 = 0; n0 < 8; ++n0) {
        int j = n0 * 16 + c15;
        float gh = acc[n0][r] + b_hh[256 + j];
        float rr = unpk(rrp[n0 * 2 + (r >> 1)], r & 1);
        float zz = unpk(zzp[n0 * 2 + (r >> 1)], r & 1);
        float gi = unpk(gip[n0 * 2 + (r >> 1)], r & 1);
        float an = fmaxf(fminf(gi + rr * gh, 15.0f), -15.0f);
        float e2 = __expf(-2.0f * an);
        float nn = (1.0f - e2) / (1.0f + e2);
        float x  = b2f(CX[row][128 + j]);
        float hv = fmaxf((1.0f - zz) * nn + zz * x, 0.0f);   // relu BEFORE LN
        h[n0] = hv; s += hv; q += hv * hv;
      }
      for (int m = 1; m < 16; m <<= 1) {
        s += __shfl_xor(s, m, 64);
        q += __shfl_xor(q, m, 64);
      }
      float mu = s * (1.0f / 128.0f);
      float var = q * (1.0f / 128.0f) - mu * mu;
      float rstd = rsqrtf(fmaxf(var, 0.0f) + G_LN_EPS);
      #pragma unroll
      for (int n0 = 0; n0 < 8; ++n0) {
        int j = n0 * 16 + c15;
        CX[row][j] = f2b((h[n0] - mu) * rstd * g1[j] + b1[j]);
      }
    }
  }

  // ---- stage kf ----
  #pragma unroll
  for (int k = 0; k < 8; ++k) {
    int i = l + k * 64;
    int r = i >> 5, seg = i & 31;
    int vn = v0 + rowbase + r; if (vn >= nV) vn = nV - 1;
    v4f kv = *(const v4f*)&kf[vn * 128 + seg * 4];
    v4s pk = { (short)f2b(kv[0]), (short)f2b(kv[1]), (short)f2b(kv[2]), (short)f2b(kv[3]) };
    *(v4s*)&CX[rowbase + r][128 + seg * 4] = pk;
  }

  // ---- stage 3 ----
  {
    v4f acc[8];
    #pragma unroll
    for (int n0 = 0; n0 < 8; ++n0)
      #pragma unroll
      for (int r = 0; r < 4; ++r) acc[n0][r] = 0.0f;
    stage_pipe8<8>((const v8s*)WcB, 8, B2,
                   &CX[rowbase + c15][0], 32, quad * 8, t, l, acc);
    #pragma unroll
    for (int r = 0; r < 4; ++r) {
      float vv[8];
      float s = 0.0f, q = 0.0f;
      #pragma unroll
      for (int n0 = 0; n0 < 8; ++n0) {
        vv[n0] = acc[n0][r] + bc[n0 * 16 + c15];
        s += vv[n0]; q += vv[n0] * vv[n0];
      }
      for (int m = 1; m < 16; m <<= 1) {
        s += __shfl_xor(s, m, 64);
        q += __shfl_xor(q, m, 64);
      }
      float mu = s * (1.0f / 128.0f);
      float var = q * (1.0f / 128.0f) - mu * mu;
      float rstd = rsqrtf(fmaxf(var, 0.0f) + G_LN_EPS);
      int vn = v0 + rowbase + quad * 4 + r;
      if (vn < nV) {
        #pragma unroll
        for (int n0 = 0; n0 < 8; ++n0) {
          int n = n0 * 16 + c15;
          float y = fmaxf((vv[n0] - mu) * rstd * g2[n] + b2[n], 0.0f);
          if (y != y) y = 9.0f;   // NaN canary
          out[vn * 128 + n] = y;
        }
      }
    }
  }
}

extern "C" void kernel_launch(void* const* d_in, const int* in_sizes, int n_in,
                              void* d_out, int out_size, void* d_ws, size_t ws_size,
                              hipStream_t stream) {
  (void)n_in;

  int nV = in_sizes[0] / 128;
  int nE = in_sizes[1];

  const float* nf     = (const float*)d_in[0];
  const int*   src    = (const int*)d_in[1];
  const int*   dst    = (const int*)d_in[2];
  const float* W_edge = (const float*)d_in[3];
  const float* b_edge = (const float*)d_in[4];
  const float* W_pn   = (const float*)d_in[5];
  const float* b_pn   = (const float*)d_in[6];
  const float* W_ih   = (const float*)d_in[7];
  const float* b_ih   = (const float*)d_in[8];
  const float* W_hh   = (const float*)d_in[9];
  const float* b_hh   = (const float*)d_in[10];
  const float* ln_g   = (const float*)d_in[11];
  const float* ln_b   = (const float*)d_in[12];
  const float* Wk1    = (const float*)d_in[13];
  const float* bk1    = (const float*)d_in[14];
  const float* lnk1_g = (const float*)d_in[15];
  const float* lnk1_b = (const float*)d_in[16];
  const float* Wk2    = (const float*)d_in[17];
  const float* bk2    = (const float*)d_in[18];
  const float* lnk2_g = (const float*)d_in[19];
  const float* lnk2_b = (const float*)d_in[20];
  const float* Wc     = (const float*)d_in[21];
  const float* bc     = (const float*)d_in[22];
  const float* lnc_g  = (const float*)d_in[23];
  const float* lnc_b  = (const float*)d_in[24];

  float* ws = (float*)d_ws;
  size_t off = 0;
  float* w_npj  = ws + off; off += (size_t)nV * G_KP;
  float* w_a    = ws + off; off += (size_t)nE;
  float* w_pd   = ws + off; off += (size_t)nV;
  float* w_ps   = ws + off; off += (size_t)nV;
  int*   w_rowp = (int*)(ws + off); off += (size_t)nV + 1;
  int*   w_curs = (int*)(ws + off); off += (size_t)nV;
  int*   w_eid  = (int*)(ws + off); off += (size_t)nE;
  int*   w_bsum = (int*)(ws + off); off += 1024;
  int*   w_boff = (int*)(ws + off); off += 1024;
  int*   w_tot  = (int*)(ws + off); off += 1;
  float* w_wctx = ws + off; off += (size_t)nV * 128;
  int*   w_deg  = (int*)(ws + off); off += (size_t)nV;       // zeroed
  float* w_kf   = ws + off; off += (size_t)nV * 128;         // zeroed
  unsigned short* w_wk2b = (unsigned short*)(ws + off); off += 26624;
  unsigned short* w_wpnb = (unsigned short*)(ws + off); off += 8192;
  unsigned short* w_wgb  = (unsigned short*)(ws + off); off += 65536;
  unsigned short* w_wcb  = (unsigned short*)(ws + off); off += 16384;
  size_t need_bytes = off * 4;

  if (ws_size < need_bytes) {   // decodable: absmax ~= 7.0
    k_fill<<<(out_size + 255) / 256, 256, 0, stream>>>((float*)d_out, out_size, 7.0f);
    return;
  }

  // sentinel: mid-pipeline death decodes as absmax ~= 2.97
  k_fill<<<(out_size + 255) / 256, 256, 0, stream>>>((float*)d_out, out_size, 2.0f);

  int nzero = nV * 129;  // deg + kf (contiguous)
  k_zero<<<(nzero + 255) / 256, 256, 0, stream>>>((float*)w_deg, nzero);
  k_prep_wk2b<<<208, 256, 0, stream>>>(Wk2, w_wk2b);
  k_prep_wpnb<<<64, 256, 0, stream>>>(W_pn, w_wpnb);
  k_prep_wgb<<<512, 256, 0, stream>>>(W_ih, W_hh, w_wgb);
  k_prep_wcb<<<128, 256, 0, stream>>>(Wc, w_wcb);

  int nB = (nV + 2047) / 2048;
  k_npj<<<(nV + 3) / 4, 256, 0, stream>>>(nf, Wk1, bk1, lnk1_g, lnk1_b,
                                          W_edge, w_npj, w_pd, w_ps, nV);
  k_hist<<<(nE + 255) / 256, 256, 0, stream>>>(dst, w_deg, nE);
  k_scan1<<<nB, 256, 0, stream>>>(w_deg, w_bsum, nV);
  k_scan2<<<1, 1024, 0, stream>>>(w_bsum, w_boff, w_tot, nB);
  k_scan3<<<nB, 256, 0, stream>>>(w_deg, w_boff, w_tot, w_rowp, w_curs, nV);
  k_edge<<<(nE + 255) / 256, 256, 0, stream>>>(src, dst, w_pd, w_ps, b_edge,
                                               w_a, w_curs, w_eid, nE);
  k_ctx_gather<<<(nV + 3) / 4, 256, 0, stream>>>(w_rowp, w_eid, src, w_a, nf,
                                                 w_wctx, nV);
  k_kron_mfma<<<(nE + 31) / 32, 256, 0, stream>>>(src, dst, w_npj, w_rowp,
                                                  w_eid, w_wk2b, bk2,
                                                  lnk2_g, lnk2_b, w_kf, nE);
  k_gru_mfma<<<(nV + 63) / 64, 256, 0, stream>>>(nf, w_wctx, w_kf, w_wpnb, b_pn,
                                                 w_wgb, b_ih, b_hh, ln_g, ln_b,
                                                 w_wcb, bc, lnc_g, lnc_b,
                                                 (float*)d_out, nV);
}